// Round 1
// baseline (200.285 us; speedup 1.0000x reference)
//
#include <hip/hip_runtime.h>
#include <hip/hip_bf16.h>

typedef __attribute__((ext_vector_type(8))) short  short8;
typedef __attribute__((ext_vector_type(4))) float  floatx4;

#define UH   2048    // U * H (row stride of inputs/hidden/out in floats)
#define XPAD 264     // 256 + 8 bf16 pad (528 B row stride, 16B aligned)

#define MFMA16(a,b,c) __builtin_amdgcn_mfma_f32_16x16x32_bf16(a, b, c, 0, 0, 0)

static __device__ __forceinline__ unsigned int pkbf16(float a, float b) {
    __hip_bfloat162 p = __float22bfloat162_rn(make_float2(a, b));
    return *(unsigned int*)&p;
}

// ---------------- prep kernel (unchanged) ------------------------------------
// Wc in MFMA-fragment order: fragment id = (u*24 + gt)*8 + s  (gt = 16-gate tile,
// s = k-step). Element lane*8+j = W[u][gt*16+(lane&15)][s*32+(lane>>4)*8+j],
// k<128 -> w_ih, else w_hh.
__global__ __launch_bounds__(256) void prep(const float* __restrict__ w_ih,
                                            const float* __restrict__ w_hh,
                                            const float* __restrict__ b_ih,
                                            const float* __restrict__ b_hh,
                                            __hip_bfloat16* __restrict__ Wc,
                                            float* __restrict__ bias_c) {
    if (blockIdx.x < 768) {
        int t   = blockIdx.x * 256 + threadIdx.x;   // [0, 196608)
        int k8  = t & 31;                           // 8-float chunk within row
        int row = t >> 5;                           // u*384 + g
        int u   = row / 384;
        int g   = row - u * 384;
        int k   = k8 * 8;
        const float* src = (k < 128) ? (w_ih + (size_t)row * 128 + k)
                                     : (w_hh + (size_t)row * 128 + (k - 128));
        float4 v0 = ((const float4*)src)[0];
        float4 v1 = ((const float4*)src)[1];
        uint4 w;
        w.x = pkbf16(v0.x, v0.y);
        w.y = pkbf16(v0.z, v0.w);
        w.z = pkbf16(v1.x, v1.y);
        w.w = pkbf16(v1.z, v1.w);
        int gt = g >> 4, lr = g & 15;
        int s  = k8 >> 2, lq = k8 & 3;
        size_t off = (size_t)((u * 24 + gt) * 8 + s) * 512 + (lq * 16 + lr) * 8;
        *(uint4*)(Wc + off) = w;
    } else {
        int idx = (blockIdx.x - 768) * 256 + threadIdx.x;   // [0, 8192)
        int u = idx >> 9;
        int g = idx & 511;
        float v;
        if (g < 256)       v = b_ih[u * 384 + g] + b_hh[u * 384 + g];
        else if (g < 384)  v = b_ih[u * 384 + g];          // xn bias
        else               v = b_hh[u * 384 + (g - 128)];  // hn bias
        bias_c[idx] = v;
    }
}

// ---------------- fused GRU kernel --------------------------------------------
// Persistent blocks: grid = 256 (1 block/CU). Block bx -> XCD (bx&7) holds
// u in {2x, 2x+1} (L2-resident 384 KB of Wc per XCD); each block owns one u
// and 8 consecutive m-tiles (64 rows each).
//   - B-fragments (24 x short8 = 96 VGPR) and bias hoisted to registers ONCE.
//   - Double-buffered Xs[2]; reg-staged async pipeline: global loads for tile
//     j+2 issued fire-and-forget, converted+ds_written one iteration later.
//   - Raw s_barrier + lgkmcnt(0)-only drain: prefetch vmcnt survives the
//     barrier (never drained to 0 in the loop) -> HBM streams under compute.
__global__ __launch_bounds__(512, 2) void gru_fused(
    const float* __restrict__ inputs, const float* __restrict__ hidden,
    const __hip_bfloat16* __restrict__ Wc, const float* __restrict__ bias_c,
    float* __restrict__ out)
{
    __shared__ __align__(16) __hip_bfloat16 Xs[2][64][XPAD];

    const int bx   = blockIdx.x;
    const int u    = ((bx & 7) << 1) | ((bx >> 3) & 1);  // XCD-local u pair
    const int mt0  = (bx >> 4) * 8;                      // first of 8 m-tiles
    const int tid  = threadIdx.x;
    const int lane = tid & 63;
    const int wv   = tid >> 6;     // [0,8): wave owns output cols [16*wv,16*wv+16)
    const int lr   = lane & 15;
    const int lq   = lane >> 4;

    // ---- hoist B fragments for this u into registers (reused for all 8 tiles)
    const short* WgU = (const short*)Wc + (size_t)u * 98304 + lane * 8;
    short8 fR[8], fZ[8], fN[8];
    #pragma unroll
    for (int s = 0; s < 8; ++s) {
        fR[s] = *(const short8*)(WgU + (size_t)(       wv * 8 + s) * 512);
        fZ[s] = *(const short8*)(WgU + (size_t)( 64 +  wv * 8 + s) * 512);
        fN[s] = *(const short8*)(WgU + (size_t)(128 +  wv * 8 + s) * 512);
    }

    // ---- bias in registers (thread's output column is fixed)
    const int   c   = wv * 16 + lr;
    const float br  = bias_c[u * 512 + c];
    const float bz  = bias_c[u * 512 + 128 + c];
    const float bxn = bias_c[u * 512 + 256 + c];
    const float bhn = bias_c[u * 512 + 384 + c];

    // ---- staging geometry: thread loads 16B at col scol, rows wv + 8*i
    const int scol = (tid & 63) * 4;                   // float col in [0,256)
    const float* sbase = ((scol < 128) ? (inputs + scol)
                                       : (hidden + (scol - 128)))
                       + (size_t)u * 128;

    float4 stg[8];   // in-flight tile (32 VGPR)

    auto ISSUE = [&](int mt) {
        const float* p = sbase + (size_t)(mt * 64 + wv) * UH;
        #pragma unroll
        for (int i = 0; i < 8; ++i)
            stg[i] = *(const float4*)(p + (size_t)(i * 8) * UH);
    };
    auto WRITE = [&](int buf) {
        #pragma unroll
        for (int i = 0; i < 8; ++i) {
            uint2 w;
            w.x = pkbf16(stg[i].x, stg[i].y);
            w.y = pkbf16(stg[i].z, stg[i].w);
            *(uint2*)&Xs[buf][i * 8 + wv][scol] = w;
        }
    };
    auto BARRIER = [&]() {
        // drain LDS only; global prefetch loads stay in flight across barrier
        asm volatile("s_waitcnt lgkmcnt(0)" ::: "memory");
        __builtin_amdgcn_sched_barrier(0);
        __builtin_amdgcn_s_barrier();
        __builtin_amdgcn_sched_barrier(0);
    };

    // ---- prologue: fill buf0, launch tile1 loads
    ISSUE(mt0 + 0);
    WRITE(0);                 // vmcnt wait on stg inserted by compiler
    ISSUE(mt0 + 1);
    BARRIER();

    #pragma unroll 1
    for (int j = 0; j < 8; ++j) {
        const int buf = j & 1;

        // ---- compute tile j from Xs[buf] (B already in registers)
        floatx4 aR[4], aZ[4], aXN[4], aHN[4];
        #pragma unroll
        for (int m4 = 0; m4 < 4; ++m4) {
            aR[m4]  = (floatx4){0.f, 0.f, 0.f, 0.f};
            aZ[m4]  = (floatx4){0.f, 0.f, 0.f, 0.f};
            aXN[m4] = (floatx4){0.f, 0.f, 0.f, 0.f};
            aHN[m4] = (floatx4){0.f, 0.f, 0.f, 0.f};
        }
        #pragma unroll
        for (int s = 0; s < 8; ++s) {
            short8 aF[4];
            #pragma unroll
            for (int m4 = 0; m4 < 4; ++m4)
                aF[m4] = *(const short8*)((const short*)&Xs[buf][m4 * 16 + lr][0]
                                          + s * 32 + lq * 8);
            #pragma unroll
            for (int m4 = 0; m4 < 4; ++m4) {
                aR[m4] = MFMA16(aF[m4], fR[s], aR[m4]);
                aZ[m4] = MFMA16(aF[m4], fZ[s], aZ[m4]);
                if (s < 4) aXN[m4] = MFMA16(aF[m4], fN[s], aXN[m4]);
                else       aHN[m4] = MFMA16(aF[m4], fN[s], aHN[m4]);
            }
        }

        // ---- epilogue: C/D layout col = lane&15, row = quad*4 + reg
        float* obase = out + (size_t)(mt0 + j) * 64 * UH + u * 128 + c;
        #pragma unroll
        for (int m4 = 0; m4 < 4; ++m4) {
            #pragma unroll
            for (int r = 0; r < 4; ++r) {
                const int m = m4 * 16 + lq * 4 + r;
                float rv = __builtin_amdgcn_rcpf(1.f + __expf(-(aR[m4][r] + br)));
                float zv = __builtin_amdgcn_rcpf(1.f + __expf(-(aZ[m4][r] + bz)));
                float npre = (aXN[m4][r] + bxn) + rv * (aHN[m4][r] + bhn);
                float nv = 2.f * __builtin_amdgcn_rcpf(1.f + __expf(-2.f * npre)) - 1.f; // tanh
                float hv = __bfloat162float(Xs[buf][m][128 + c]);  // original hidden
                obase[(size_t)m * UH] = nv + zv * (hv - nv);
            }
        }

        // ---- pipeline: land tile j+1 into the other buffer, launch tile j+2
        if (j < 7) {
            WRITE(buf ^ 1);                  // waits only on its own stg vmcnt
            if (j < 6) ISSUE(mt0 + j + 2);   // fire-and-forget across barrier
            BARRIER();
        }
    }
}

// ---------------- launch ------------------------------------------------------

extern "C" void kernel_launch(void* const* d_in, const int* in_sizes, int n_in,
                              void* d_out, int out_size, void* d_ws, size_t ws_size,
                              hipStream_t stream) {
    const float* inputs = (const float*)d_in[0];
    const float* hidden = (const float*)d_in[1];
    const float* w_ih   = (const float*)d_in[2];
    const float* w_hh   = (const float*)d_in[3];
    const float* b_ih   = (const float*)d_in[4];
    const float* b_hh   = (const float*)d_in[5];
    float* out = (float*)d_out;

    __hip_bfloat16* Wc = (__hip_bfloat16*)d_ws;
    float* bias_c = (float*)((char*)d_ws + (size_t)16 * 384 * 256 * 2);  // +3,145,728 B

    prep<<<dim3(800), dim3(256), 0, stream>>>(w_ih, w_hh, b_ih, b_hh, Wc, bias_c);
    gru_fused<<<dim3(256), dim3(512), 0, stream>>>(inputs, hidden, Wc, bias_c, out);
}